// Round 7
// baseline (123.355 us; speedup 1.0000x reference)
//
#include <hip/hip_runtime.h>
#include <math.h>

#define NCH 384
#define RNK 5
#define NA  32
#define NSTART 384            // starts < NCH-NA+1 = 353; 384 bins for safety
#define CAP 1024              // per-bucket slot cap (avg ~186 for n=65536)
#define BPB    8              // blocks per bucket
#define SLICES 32             // wave-slices per bucket = BPB * 4 waves
#define TILE_W 192            // 160 numerator + 32 nan-weight partials
#define MAX_PER 16
#define FLT_BIG 3.402823466e38f

// ---- ws word layout ----
#define WS_TOT   0                        // 1 f32 (total weight)
#define WS_MIN   1                        // 1 u32 (encoded min of lik_data)
#define WS_CUR   2                        // NSTART u32 (bucket fill counters)
#define WS_ORDER (WS_CUR + NSTART)        // NSTART*CAP u32
#define WS_TILE  (WS_ORDER + NSTART*CAP)  // NSTART*BPB*TILE_W f32
#define WS_WORDS (WS_TILE + NSTART*BPB*TILE_W)
#define WS_INIT_WORDS (WS_CUR + NSTART)   // zero/seed [0, WS_CUR+NSTART)

__device__ __forceinline__ bool finitef(float v) {
    return fabsf(v) <= FLT_BIG;   // NaN fails, +-inf exceeds
}
__device__ __forceinline__ unsigned fenc(float f) {
    unsigned u = __float_as_uint(f);
    return (u & 0x80000000u) ? ~u : (u | 0x80000000u);
}
__device__ __forceinline__ float fdec(unsigned u) {
    unsigned b = (u & 0x80000000u) ? (u ^ 0x80000000u) : ~u;
    return __uint_as_float(b);
}

// ---- pass 0: init (no hipMemsetAsync in-graph: rocclr fill ~40us) ----
__global__ void init_ws_kernel(unsigned* __restrict__ ws) {
    int i = blockIdx.x * blockDim.x + threadIdx.x;
    if (i < WS_INIT_WORDS) ws[i] = (i == WS_MIN) ? 0xFFFFFFFFu : 0u;
}

// ---- pass 1: bucket scatter (spread: block b owns spikes b*32+lane,
// its 32 channel reads land in one 4KB window) + total-weight / lik-min
// folded to ONE single-address atomic per block (no reduce kernel) ----
__global__ __launch_bounds__(256) void prep_kernel(
    const int* __restrict__ channels, const float* __restrict__ weights,
    const float* __restrict__ lik_data, int n, int nnz,
    unsigned* __restrict__ ws_u, float* __restrict__ ws_f)
{
    const int tid  = threadIdx.x;
    const int lane = tid & 63;
    const int wave = tid >> 6;

    float tw = 0.f;
    if (tid < 32) {
        const int sp = blockIdx.x * 32 + tid;
        if (sp < n) {
            const int st = channels[(size_t)sp * NA];  // channels[sp][0]
            unsigned pos = atomicAdd(&ws_u[WS_CUR + st], 1u);
            if (pos < CAP)
                ws_u[WS_ORDER + (size_t)st * CAP + pos] = (unsigned)sp;
            tw = weights[sp];
        }
    }

    float m = FLT_BIG;
    const int gtid = blockIdx.x * 256 + tid;
    const int gstride = gridDim.x * 256;
    const int n4 = nnz >> 2;
    const float4* d4 = (const float4*)lik_data;
    for (int j = gtid; j < n4; j += gstride) {
        float4 v = d4[j];
        m = fminf(m, fminf(fminf(v.x, v.y), fminf(v.z, v.w)));
    }
    for (int j = (n4 << 2) + gtid; j < nnz; j += gstride)
        m = fminf(m, lik_data[j]);

    #pragma unroll
    for (int o = 32; o; o >>= 1) {
        tw += __shfl_down(tw, o);
        m = fminf(m, __shfl_down(m, o));
    }
    __shared__ float swt[4], swm[4];
    if (lane == 0) { swt[wave] = tw; swm[wave] = m; }
    __syncthreads();
    if (tid == 0) {
        float t = swt[0] + swt[1] + swt[2] + swt[3];
        if (t != 0.f) atomicAdd(&ws_f[WS_TOT], t);
        float mm = fminf(fminf(swm[0], swm[1]), fminf(swm[2], swm[3]));
        atomicMin(&ws_u[WS_MIN], fenc(mm));
    }
}

// ---- pass 2: bucketed accumulation -> private partial tiles ----
// bucket b covers channels [b, b+NA). lane owns tile elems {lane, lane+64}
// (+ lane+128 for lane<32); elem e = r*32 + a.
__global__ __launch_bounds__(256) void accum_kernel(
    const float* __restrict__ feats, const float* __restrict__ weights,
    const unsigned* __restrict__ ws_u, float* __restrict__ ws2)
{
    __shared__ float s_tile[TILE_W];
    const int bid  = blockIdx.x;
    const int b    = bid >> 3;          // bid / BPB
    const int j    = bid & (BPB - 1);
    const int tid  = threadIdx.x;
    const int wave = tid >> 6;
    const int lane = tid & 63;
    const int slice = j * 4 + wave;
    int cnt = (int)ws_u[WS_CUR + b];
    if (cnt > CAP) cnt = CAP;
    const unsigned* order = ws_u + WS_ORDER + (size_t)b * CAP;

    for (int i = tid; i < TILE_W; i += 256) s_tile[i] = 0.f;
    __syncthreads();

    float acc0 = 0.f, acc1 = 0.f, acc2 = 0.f, nanw = 0.f;
    int spike = 0; float w = 0.f;
    if (slice < cnt) { spike = (int)order[slice]; w = weights[spike]; }
    for (int k = slice; k < cnt; k += SLICES) {
        const float* f = feats + (size_t)spike * (RNK * NA);
        int nspike = 0; float nw = 0.f;
        if (k + SLICES < cnt) {            // prefetch next (spike, weight)
            nspike = (int)order[k + SLICES];
            nw = weights[nspike];
        }
        const float v0 = f[lane];          // elems [0,64)   ranks 0-1
        const float v1 = f[lane + 64];     // elems [64,128) ranks 2-3
        const float v2 = (lane < 32) ? f[lane + 128] : 0.f;  // rank 4
        const float r0 = __shfl(v0, lane & 31);  // rank-0 value of column a
        if (finitef(r0)) {
            acc0 += w * (finitef(v0) ? v0 : 0.f);
            acc1 += w * (finitef(v1) ? v1 : 0.f);
            if (lane < 32) acc2 += w * (finitef(v2) ? v2 : 0.f);
        } else if (lane < 32) {
            nanw += w;
        }
        spike = nspike; w = nw;
    }

    atomicAdd(&s_tile[lane], acc0);
    atomicAdd(&s_tile[64 + lane], acc1);
    if (lane < 32) {
        atomicAdd(&s_tile[128 + lane], acc2);
        atomicAdd(&s_tile[160 + lane], nanw);
    }
    __syncthreads();

    float* dst = ws2 + (size_t)bid * TILE_W;   // private slot: plain stores
    for (int i = tid; i < TILE_W; i += 256) dst[i] = s_tile[i];
}

// ---- pass 3 (fused): assignments + emp_mean wave-gather ----
__global__ __launch_bounds__(256) void final_kernel(
    const int* __restrict__ rows, const float* __restrict__ data,
    const float* __restrict__ ws_f, const unsigned* __restrict__ ws_u,
    const float* __restrict__ ws2, float* __restrict__ out,
    int n, int per, int assign_blocks)
{
    const int tid = threadIdx.x;
    if ((int)blockIdx.x >= assign_blocks) {
        // emp_mean: one WAVE per output element; lanes split (db, slice-half)
        const int widx = (blockIdx.x - assign_blocks) * 4 + (tid >> 6);
        const int lane = tid & 63;
        if (widx < RNK * NCH) {
            const int c = widx % NCH;
            const int r = widx / NCH;
            const int db = lane & 31;
            const int half = lane >> 5;
            float s = 0.f, nb = 0.f;
            const int b = c - db;
            if (b >= 0) {
                #pragma unroll
                for (int jj = 0; jj < BPB / 2; ++jj) {
                    const float* t =
                        ws2 + ((size_t)b * BPB + (jj * 2 + half)) * TILE_W;
                    s  += t[r * 32 + db];
                    nb += t[160 + db];
                }
            }
            #pragma unroll
            for (int o = 32; o; o >>= 1) {
                s  += __shfl_down(s, o);
                nb += __shfl_down(nb, o);
            }
            if (lane == 0) out[widx] = s / (ws_f[WS_TOT] - nb);
        }
        return;
    }

    // assignments: LDS-staged argmax with min-row tie-break
    __shared__ float sd[256 * MAX_PER];
    __shared__ int   sr[256 * MAX_PER];
    const int base = blockIdx.x * 256;
    const float offset = fdec(ws_u[WS_MIN]) - 1.0f;

    if (per <= MAX_PER) {
        const int lim = min(256, n - base) * per;
        const size_t gbase = (size_t)base * per;
        for (int i = tid; i < lim; i += 256) {
            sd[i] = data[gbase + i];
            sr[i] = rows[gbase + i];
        }
        __syncthreads();
        const int spike = base + tid;
        if (spike >= n) return;
        float best_s = -FLT_BIG;
        int best_row = 0x7FFFFFFF;
        const int o = tid * per;
        for (int j = 0; j < per; ++j) {
            float s = sd[o + j] - offset;    // same f32 op as reference
            int r = sr[o + j];
            if (s > best_s) { best_s = s; best_row = r; }
            else if (s == best_s && r < best_row) best_row = r;
        }
        out[RNK * NCH + spike] = (float)best_row;
    } else {
        const int spike = base + tid;
        if (spike >= n) return;
        const float* d  = data + (size_t)spike * per;
        const int*   rr = rows + (size_t)spike * per;
        float best_s = -FLT_BIG;
        int best_row = 0x7FFFFFFF;
        for (int j = 0; j < per; ++j) {
            float s = d[j] - offset;
            int r = rr[j];
            if (s > best_s) { best_s = s; best_row = r; }
            else if (s == best_s && r < best_row) best_row = r;
        }
        out[RNK * NCH + spike] = (float)best_row;
    }
}

// ---- fallback path (ws too small): LDS-atomic accumulation ----
#define FB_NUM   0
#define FB_NANW  (RNK*NCH)
#define FB_TOT   (FB_NANW + NCH)
#define FB_MIN   (FB_TOT + 1)
#define FB_WORDS (FB_MIN + 1)

__global__ void fb_init_kernel(unsigned* __restrict__ ws) {
    int i = blockIdx.x * blockDim.x + threadIdx.x;
    if (i < FB_WORDS) ws[i] = (i == FB_MIN) ? 0xFFFFFFFFu : 0u;
}
__global__ __launch_bounds__(256) void fb_accum_kernel(
    const float* __restrict__ feats, const int* __restrict__ channels,
    const float* __restrict__ weights, float* __restrict__ ws, int n)
{
    __shared__ float s_num[RNK * NCH];
    __shared__ float s_nanw[NCH];
    __shared__ float s_total;
    const int tid = threadIdx.x;
    for (int i = tid; i < RNK * NCH; i += 256) s_num[i] = 0.f;
    for (int i = tid; i < NCH; i += 256) s_nanw[i] = 0.f;
    if (tid == 0) s_total = 0.f;
    __syncthreads();
    const int total = n * NA;
    const int stride = gridDim.x * blockDim.x;
    float tw = 0.f;
    for (int idx = blockIdx.x * blockDim.x + tid; idx < total; idx += stride) {
        const int spike = idx >> 5, a = idx & (NA - 1);
        const int ch = channels[idx];
        const float w = weights[spike];
        if (a == 0) tw += w;
        const float* f = feats + (size_t)spike * (RNK * NA) + a;
        const float v0 = f[0];
        if (finitef(v0)) {
            atomicAdd(&s_num[ch], w * v0);
            #pragma unroll
            for (int r = 1; r < RNK; ++r) {
                float v = f[r * NA];
                if (!finitef(v)) v = 0.f;
                atomicAdd(&s_num[r * NCH + ch], w * v);
            }
        } else atomicAdd(&s_nanw[ch], w);
    }
    #pragma unroll
    for (int off = 32; off; off >>= 1) tw += __shfl_down(tw, off);
    if ((tid & 63) == 0) atomicAdd(&s_total, tw);
    __syncthreads();
    for (int i = tid; i < RNK * NCH; i += 256)
        if (s_num[i] != 0.f) atomicAdd(&ws[FB_NUM + i], s_num[i]);
    for (int i = tid; i < NCH; i += 256)
        if (s_nanw[i] != 0.f) atomicAdd(&ws[FB_NANW + i], s_nanw[i]);
    if (tid == 0) atomicAdd(&ws[FB_TOT], s_total);
}
__global__ void fb_min_kernel(const float* __restrict__ data, int nnz,
                              unsigned* __restrict__ minw) {
    float m = FLT_BIG;
    for (int i = blockIdx.x * blockDim.x + threadIdx.x; i < nnz;
         i += gridDim.x * blockDim.x) m = fminf(m, data[i]);
    #pragma unroll
    for (int off = 32; off; off >>= 1) m = fminf(m, __shfl_down(m, off));
    if ((threadIdx.x & 63) == 0) atomicMin(minw, fenc(m));
}
__global__ void fb_finalize_kernel(const float* __restrict__ ws,
                                   float* __restrict__ out) {
    int i = blockIdx.x * blockDim.x + threadIdx.x;
    if (i < RNK * NCH) {
        int c = i % NCH;
        float cnt = ws[FB_TOT] - ws[FB_NANW + c];
        out[i] = ws[FB_NUM + i] / cnt;
    }
}
__global__ __launch_bounds__(256) void fb_assign_kernel(
    const int* __restrict__ rows, const float* __restrict__ data,
    const unsigned* __restrict__ minw, float* __restrict__ out, int n, int per)
{
    const int spike = blockIdx.x * 256 + threadIdx.x;
    if (spike >= n) return;
    const float offset = fdec(*minw) - 1.0f;
    const float* d  = data + (size_t)spike * per;
    const int*   rr = rows + (size_t)spike * per;
    float best_s = -FLT_BIG;
    int best_row = 0x7FFFFFFF;
    for (int j = 0; j < per; ++j) {
        float s = d[j] - offset;
        int r = rr[j];
        if (s > best_s) { best_s = s; best_row = r; }
        else if (s == best_s && r < best_row) best_row = r;
    }
    out[RNK * NCH + spike] = (float)best_row;
}

extern "C" void kernel_launch(void* const* d_in, const int* in_sizes, int n_in,
                              void* d_out, int out_size, void* d_ws, size_t ws_size,
                              hipStream_t stream) {
    const float* feats    = (const float*)d_in[0];
    const int*   channels = (const int*)d_in[1];
    const float* weights  = (const float*)d_in[2];
    const int*   lik_rows = (const int*)d_in[3];
    const float* lik_data = (const float*)d_in[5];

    int n   = in_sizes[2];
    int nnz = in_sizes[3];
    int per = nnz / n;

    float*    out = (float*)d_out;
    unsigned* wsu = (unsigned*)d_ws;
    float*    wsf = (float*)d_ws;

    const size_t req_bytes = (size_t)WS_WORDS * 4;
    const bool cap_ok = (n <= NSTART * CAP / 2);   // huge margin vs uniform starts

    if (ws_size >= req_bytes && cap_ok) {
        const int assign_blocks = (n + 255) / 256;
        const int emp_blk = (RNK * NCH + 3) / 4;   // 4 waves (=4 elems) per block
        int prep_grid = (n + 31) / 32;
        if (prep_grid < 1024) prep_grid = 1024;
        init_ws_kernel<<<(WS_INIT_WORDS + 255) / 256, 256, 0, stream>>>(wsu);
        prep_kernel<<<prep_grid, 256, 0, stream>>>(
            channels, weights, lik_data, n, nnz, wsu, wsf);
        accum_kernel<<<NSTART * BPB, 256, 0, stream>>>(
            feats, weights, wsu, wsf + WS_TILE);
        final_kernel<<<assign_blocks + emp_blk, 256, 0, stream>>>(
            lik_rows, lik_data, wsf, wsu, wsf + WS_TILE, out, n, per,
            assign_blocks);
    } else {
        fb_init_kernel<<<(FB_WORDS + 255) / 256, 256, 0, stream>>>(wsu);
        fb_accum_kernel<<<1024, 256, 0, stream>>>(feats, channels, weights, wsf, n);
        fb_finalize_kernel<<<(RNK * NCH + 255) / 256, 256, 0, stream>>>(wsf, out);
        fb_min_kernel<<<256, 256, 0, stream>>>(lik_data, nnz, wsu + FB_MIN);
        fb_assign_kernel<<<(n + 255) / 256, 256, 0, stream>>>(
            lik_rows, lik_data, wsu + FB_MIN, out, n, per);
    }
}

// Round 8
// 54.241 us; speedup vs baseline: 2.2742x; 2.2742x over previous
//
#include <hip/hip_runtime.h>
#include <math.h>

#define NCH 384
#define RNK 5
#define NA  32
#define NSTART 384            // starts < NCH-NA+1 = 353; 384 bins for safety
#define NREP 8                // counter/sub-list replicas per bucket (anti-contention)
#define CAPR 128              // slots per (bucket, replica) sub-list
#define CAP (NREP*CAPR)       // 1024 slots per bucket total
#define PREP_GRID 2048
#define BPB    8              // blocks per bucket == NREP (block j eats sub-list j)
#define TILE_W 192            // 160 numerator + 32 nan-weight partials
#define MAX_PER 16
#define FLT_BIG 3.402823466e38f

// ---- ws word layout ----
#define WS_TOT   0                          // 1 f32 (total weight, final)
#define WS_MIN   1                          // 1 f32 (min of lik_data, final)
#define WS_CUR   2                          // NSTART*NREP u32 fill counters
#define WS_TOTP  (WS_CUR + NSTART*NREP)     // PREP_GRID f32 partial totals
#define WS_MINP  (WS_TOTP + PREP_GRID)      // PREP_GRID f32 partial mins
#define WS_ORDER (WS_MINP + PREP_GRID)      // NSTART*CAP u32
#define WS_TILE  (WS_ORDER + NSTART*CAP)    // NSTART*BPB*TILE_W f32
#define WS_WORDS (WS_TILE + NSTART*BPB*TILE_W)
#define WS_INIT_WORDS (WS_CUR + NSTART*NREP)   // zero [0, ...)

__device__ __forceinline__ bool finitef(float v) {
    return fabsf(v) <= FLT_BIG;   // NaN fails, +-inf exceeds
}
__device__ __forceinline__ unsigned fenc(float f) {
    unsigned u = __float_as_uint(f);
    return (u & 0x80000000u) ? ~u : (u | 0x80000000u);
}
__device__ __forceinline__ float fdec(unsigned u) {
    unsigned b = (u & 0x80000000u) ? (u ^ 0x80000000u) : ~u;
    return __uint_as_float(b);
}

// ---- pass 0: init (no hipMemsetAsync in-graph: rocclr fill ~40us) ----
__global__ void init_ws_kernel(unsigned* __restrict__ ws) {
    int i = blockIdx.x * blockDim.x + threadIdx.x;
    if (i < WS_INIT_WORDS) ws[i] = 0u;
}

// ---- pass 1: replicated bucket scatter + per-block partials (NO same-
// address atomic funnels: that was R7's 83us prep) ----
__global__ __launch_bounds__(256) void prep_kernel(
    const int* __restrict__ channels, const float* __restrict__ weights,
    const float* __restrict__ lik_data, int n, int nnz,
    unsigned* __restrict__ ws_u, float* __restrict__ ws_f)
{
    const int tid  = threadIdx.x;
    const int lane = tid & 63;
    const int wave = tid >> 6;
    const int rep  = blockIdx.x & (NREP - 1);

    float tw = 0.f;
    if (tid < 32) {
        for (int sp0 = blockIdx.x * 32; sp0 < n; sp0 += gridDim.x * 32) {
            const int sp = sp0 + tid;
            if (sp < n) {
                const int st = channels[(size_t)sp * NA];  // channels[sp][0]
                unsigned pos = atomicAdd(&ws_u[WS_CUR + st * NREP + rep], 1u);
                if (pos < CAPR)
                    ws_u[WS_ORDER + (size_t)st * CAP + rep * CAPR + pos] =
                        (unsigned)sp;
                tw += weights[sp];
            }
        }
    }

    float m = FLT_BIG;
    const int gtid = blockIdx.x * 256 + tid;
    const int gstride = gridDim.x * 256;
    const int n4 = nnz >> 2;
    const float4* d4 = (const float4*)lik_data;
    for (int j = gtid; j < n4; j += gstride) {
        float4 v = d4[j];
        m = fminf(m, fminf(fminf(v.x, v.y), fminf(v.z, v.w)));
    }
    for (int j = (n4 << 2) + gtid; j < nnz; j += gstride)
        m = fminf(m, lik_data[j]);

    #pragma unroll
    for (int o = 32; o; o >>= 1) {
        tw += __shfl_down(tw, o);
        m = fminf(m, __shfl_down(m, o));
    }
    __shared__ float swt[4], swm[4];
    if (lane == 0) { swt[wave] = tw; swm[wave] = m; }
    __syncthreads();
    if (tid == 0) {        // plain stores to private slots — no funnel
        ws_f[WS_TOTP + blockIdx.x] = swt[0] + swt[1] + swt[2] + swt[3];
        ws_f[WS_MINP + blockIdx.x] =
            fminf(fminf(swm[0], swm[1]), fminf(swm[2], swm[3]));
    }
}

// ---- pass 2: fold the 2048 per-block partials (single block, ~3us) ----
__global__ __launch_bounds__(512) void reduce_kernel(float* __restrict__ ws_f)
{
    __shared__ float st[512], sm[512];
    const int tid = threadIdx.x;
    float t = 0.f, m = FLT_BIG;
    for (int i = tid; i < PREP_GRID; i += 512) {
        t += ws_f[WS_TOTP + i];
        m = fminf(m, ws_f[WS_MINP + i]);
    }
    st[tid] = t; sm[tid] = m;
    __syncthreads();
    for (int s = 256; s; s >>= 1) {
        if (tid < s) {
            st[tid] += st[tid + s];
            sm[tid] = fminf(sm[tid], sm[tid + s]);
        }
        __syncthreads();
    }
    if (tid == 0) { ws_f[WS_TOT] = st[0]; ws_f[WS_MIN] = sm[0]; }
}

// ---- pass 3: bucketed accumulation -> private partial tiles ----
// block j of bucket b consumes exactly replica-sub-list j (~n/NSTART/NREP
// spikes). lane owns tile elems {lane, lane+64} (+ lane+128 for lane<32).
__global__ __launch_bounds__(256) void accum_kernel(
    const float* __restrict__ feats, const float* __restrict__ weights,
    const unsigned* __restrict__ ws_u, float* __restrict__ ws2)
{
    __shared__ float s_tile[TILE_W];
    const int bid  = blockIdx.x;
    const int b    = bid >> 3;          // bid / BPB
    const int rep  = bid & (BPB - 1);
    const int tid  = threadIdx.x;
    const int wave = tid >> 6;
    const int lane = tid & 63;
    int cnt = (int)ws_u[WS_CUR + b * NREP + rep];
    if (cnt > CAPR) cnt = CAPR;
    const unsigned* order = ws_u + WS_ORDER + (size_t)b * CAP + rep * CAPR;

    for (int i = tid; i < TILE_W; i += 256) s_tile[i] = 0.f;
    __syncthreads();

    float acc0 = 0.f, acc1 = 0.f, acc2 = 0.f, nanw = 0.f;
    int spike = 0; float w = 0.f;
    if (wave < cnt) { spike = (int)order[wave]; w = weights[spike]; }
    for (int k = wave; k < cnt; k += 4) {
        const float* f = feats + (size_t)spike * (RNK * NA);
        int nspike = 0; float nw = 0.f;
        if (k + 4 < cnt) {                 // prefetch next (spike, weight)
            nspike = (int)order[k + 4];
            nw = weights[nspike];
        }
        const float v0 = f[lane];          // elems [0,64)   ranks 0-1
        const float v1 = f[lane + 64];     // elems [64,128) ranks 2-3
        const float v2 = (lane < 32) ? f[lane + 128] : 0.f;  // rank 4
        const float r0 = __shfl(v0, lane & 31);  // rank-0 value of column a
        if (finitef(r0)) {
            acc0 += w * (finitef(v0) ? v0 : 0.f);
            acc1 += w * (finitef(v1) ? v1 : 0.f);
            if (lane < 32) acc2 += w * (finitef(v2) ? v2 : 0.f);
        } else if (lane < 32) {
            nanw += w;
        }
        spike = nspike; w = nw;
    }

    atomicAdd(&s_tile[lane], acc0);
    atomicAdd(&s_tile[64 + lane], acc1);
    if (lane < 32) {
        atomicAdd(&s_tile[128 + lane], acc2);
        atomicAdd(&s_tile[160 + lane], nanw);
    }
    __syncthreads();

    float* dst = ws2 + (size_t)bid * TILE_W;   // private slot: plain stores
    for (int i = tid; i < TILE_W; i += 256) dst[i] = s_tile[i];
}

// ---- pass 4 (fused): assignments + emp_mean wave-gather ----
__global__ __launch_bounds__(256) void final_kernel(
    const int* __restrict__ rows, const float* __restrict__ data,
    const float* __restrict__ ws_f, const float* __restrict__ ws2,
    float* __restrict__ out, int n, int per, int assign_blocks)
{
    const int tid = threadIdx.x;
    if ((int)blockIdx.x >= assign_blocks) {
        // emp_mean: one WAVE per output element; lanes split (db, slice-half)
        const int widx = (blockIdx.x - assign_blocks) * 4 + (tid >> 6);
        const int lane = tid & 63;
        if (widx < RNK * NCH) {
            const int c = widx % NCH;
            const int r = widx / NCH;
            const int db = lane & 31;
            const int half = lane >> 5;
            float s = 0.f, nb = 0.f;
            const int b = c - db;
            if (b >= 0) {
                #pragma unroll
                for (int jj = 0; jj < BPB / 2; ++jj) {
                    const float* t =
                        ws2 + ((size_t)b * BPB + (jj * 2 + half)) * TILE_W;
                    s  += t[r * 32 + db];
                    nb += t[160 + db];
                }
            }
            #pragma unroll
            for (int o = 32; o; o >>= 1) {
                s  += __shfl_down(s, o);
                nb += __shfl_down(nb, o);
            }
            if (lane == 0) out[widx] = s / (ws_f[WS_TOT] - nb);
        }
        return;
    }

    // assignments: LDS-staged argmax with min-row tie-break
    __shared__ float sd[256 * MAX_PER];
    __shared__ int   sr[256 * MAX_PER];
    const int base = blockIdx.x * 256;
    const float offset = ws_f[WS_MIN] - 1.0f;

    if (per <= MAX_PER) {
        const int lim = min(256, n - base) * per;
        const size_t gbase = (size_t)base * per;
        for (int i = tid; i < lim; i += 256) {
            sd[i] = data[gbase + i];
            sr[i] = rows[gbase + i];
        }
        __syncthreads();
        const int spike = base + tid;
        if (spike >= n) return;
        float best_s = -FLT_BIG;
        int best_row = 0x7FFFFFFF;
        const int o = tid * per;
        for (int j = 0; j < per; ++j) {
            float s = sd[o + j] - offset;    // same f32 op as reference
            int r = sr[o + j];
            if (s > best_s) { best_s = s; best_row = r; }
            else if (s == best_s && r < best_row) best_row = r;
        }
        out[RNK * NCH + spike] = (float)best_row;
    } else {
        const int spike = base + tid;
        if (spike >= n) return;
        const float* d  = data + (size_t)spike * per;
        const int*   rr = rows + (size_t)spike * per;
        float best_s = -FLT_BIG;
        int best_row = 0x7FFFFFFF;
        for (int j = 0; j < per; ++j) {
            float s = d[j] - offset;
            int r = rr[j];
            if (s > best_s) { best_s = s; best_row = r; }
            else if (s == best_s && r < best_row) best_row = r;
        }
        out[RNK * NCH + spike] = (float)best_row;
    }
}

// ---- fallback path (ws too small): LDS-atomic accumulation ----
#define FB_NUM   0
#define FB_NANW  (RNK*NCH)
#define FB_TOT   (FB_NANW + NCH)
#define FB_MIN   (FB_TOT + 1)
#define FB_WORDS (FB_MIN + 1)

__global__ void fb_init_kernel(unsigned* __restrict__ ws) {
    int i = blockIdx.x * blockDim.x + threadIdx.x;
    if (i < FB_WORDS) ws[i] = (i == FB_MIN) ? 0xFFFFFFFFu : 0u;
}
__global__ __launch_bounds__(256) void fb_accum_kernel(
    const float* __restrict__ feats, const int* __restrict__ channels,
    const float* __restrict__ weights, float* __restrict__ ws, int n)
{
    __shared__ float s_num[RNK * NCH];
    __shared__ float s_nanw[NCH];
    __shared__ float s_total;
    const int tid = threadIdx.x;
    for (int i = tid; i < RNK * NCH; i += 256) s_num[i] = 0.f;
    for (int i = tid; i < NCH; i += 256) s_nanw[i] = 0.f;
    if (tid == 0) s_total = 0.f;
    __syncthreads();
    const int total = n * NA;
    const int stride = gridDim.x * blockDim.x;
    float tw = 0.f;
    for (int idx = blockIdx.x * blockDim.x + tid; idx < total; idx += stride) {
        const int spike = idx >> 5, a = idx & (NA - 1);
        const int ch = channels[idx];
        const float w = weights[spike];
        if (a == 0) tw += w;
        const float* f = feats + (size_t)spike * (RNK * NA) + a;
        const float v0 = f[0];
        if (finitef(v0)) {
            atomicAdd(&s_num[ch], w * v0);
            #pragma unroll
            for (int r = 1; r < RNK; ++r) {
                float v = f[r * NA];
                if (!finitef(v)) v = 0.f;
                atomicAdd(&s_num[r * NCH + ch], w * v);
            }
        } else atomicAdd(&s_nanw[ch], w);
    }
    #pragma unroll
    for (int off = 32; off; off >>= 1) tw += __shfl_down(tw, off);
    if ((tid & 63) == 0) atomicAdd(&s_total, tw);
    __syncthreads();
    for (int i = tid; i < RNK * NCH; i += 256)
        if (s_num[i] != 0.f) atomicAdd(&ws[FB_NUM + i], s_num[i]);
    for (int i = tid; i < NCH; i += 256)
        if (s_nanw[i] != 0.f) atomicAdd(&ws[FB_NANW + i], s_nanw[i]);
    if (tid == 0) atomicAdd(&ws[FB_TOT], s_total);
}
__global__ void fb_min_kernel(const float* __restrict__ data, int nnz,
                              unsigned* __restrict__ minw) {
    float m = FLT_BIG;
    for (int i = blockIdx.x * blockDim.x + threadIdx.x; i < nnz;
         i += gridDim.x * blockDim.x) m = fminf(m, data[i]);
    #pragma unroll
    for (int off = 32; off; off >>= 1) m = fminf(m, __shfl_down(m, off));
    if ((threadIdx.x & 63) == 0) atomicMin(minw, fenc(m));
}
__global__ void fb_finalize_kernel(const float* __restrict__ ws,
                                   float* __restrict__ out) {
    int i = blockIdx.x * blockDim.x + threadIdx.x;
    if (i < RNK * NCH) {
        int c = i % NCH;
        float cnt = ws[FB_TOT] - ws[FB_NANW + c];
        out[i] = ws[FB_NUM + i] / cnt;
    }
}
__global__ __launch_bounds__(256) void fb_assign_kernel(
    const int* __restrict__ rows, const float* __restrict__ data,
    const unsigned* __restrict__ minw, float* __restrict__ out, int n, int per)
{
    const int spike = blockIdx.x * 256 + threadIdx.x;
    if (spike >= n) return;
    const float offset = fdec(*minw) - 1.0f;
    const float* d  = data + (size_t)spike * per;
    const int*   rr = rows + (size_t)spike * per;
    float best_s = -FLT_BIG;
    int best_row = 0x7FFFFFFF;
    for (int j = 0; j < per; ++j) {
        float s = d[j] - offset;
        int r = rr[j];
        if (s > best_s) { best_s = s; best_row = r; }
        else if (s == best_s && r < best_row) best_row = r;
    }
    out[RNK * NCH + spike] = (float)best_row;
}

extern "C" void kernel_launch(void* const* d_in, const int* in_sizes, int n_in,
                              void* d_out, int out_size, void* d_ws, size_t ws_size,
                              hipStream_t stream) {
    const float* feats    = (const float*)d_in[0];
    const int*   channels = (const int*)d_in[1];
    const float* weights  = (const float*)d_in[2];
    const int*   lik_rows = (const int*)d_in[3];
    const float* lik_data = (const float*)d_in[5];

    int n   = in_sizes[2];
    int nnz = in_sizes[3];
    int per = nnz / n;

    float*    out = (float*)d_out;
    unsigned* wsu = (unsigned*)d_ws;
    float*    wsf = (float*)d_ws;

    const size_t req_bytes = (size_t)WS_WORDS * 4;
    // sub-list margin: avg fill n/(NSTART*NREP) must be << CAPR
    const bool cap_ok = (n <= NSTART * NREP * CAPR / 4);

    if (ws_size >= req_bytes && cap_ok) {
        const int assign_blocks = (n + 255) / 256;
        const int emp_blk = (RNK * NCH + 3) / 4;   // 4 waves (=4 elems) per block
        init_ws_kernel<<<(WS_INIT_WORDS + 255) / 256, 256, 0, stream>>>(wsu);
        prep_kernel<<<PREP_GRID, 256, 0, stream>>>(
            channels, weights, lik_data, n, nnz, wsu, wsf);
        reduce_kernel<<<1, 512, 0, stream>>>(wsf);
        accum_kernel<<<NSTART * BPB, 256, 0, stream>>>(
            feats, weights, wsu, wsf + WS_TILE);
        final_kernel<<<assign_blocks + emp_blk, 256, 0, stream>>>(
            lik_rows, lik_data, wsf, wsf + WS_TILE, out, n, per, assign_blocks);
    } else {
        fb_init_kernel<<<(FB_WORDS + 255) / 256, 256, 0, stream>>>(wsu);
        fb_accum_kernel<<<1024, 256, 0, stream>>>(feats, channels, weights, wsf, n);
        fb_finalize_kernel<<<(RNK * NCH + 255) / 256, 256, 0, stream>>>(wsf, out);
        fb_min_kernel<<<256, 256, 0, stream>>>(lik_data, nnz, wsu + FB_MIN);
        fb_assign_kernel<<<(n + 255) / 256, 256, 0, stream>>>(
            lik_rows, lik_data, wsu + FB_MIN, out, n, per);
    }
}